// Round 4
// baseline (1023.818 us; speedup 1.0000x reference)
//
#include <hip/hip_runtime.h>
#include <math.h>

// Problem constants
#define NTOK  16384   // B*T
#define DDIM  1024
#define NDOCS 4096

typedef __attribute__((ext_vector_type(8))) short short8;
typedef __attribute__((ext_vector_type(4))) float f32x4;

__device__ __forceinline__ float b2f(unsigned short u){
  union { unsigned int i; float f; } v; v.i = ((unsigned int)u) << 16; return v.f;
}
__device__ __forceinline__ unsigned short f2b(float f){
  union { float f; unsigned int i; } v; v.f = f;
  unsigned int r = v.i + 0x7fffu + ((v.i >> 16) & 1u);   // RNE
  return (unsigned short)(r >> 16);
}
// dtype-flexible scalar load: flag==1 -> f32 buffer, flag==0 -> bf16 buffer
__device__ __forceinline__ float ldf(const void* p, size_t i, int f32){
  return f32 ? ((const float*)p)[i] : b2f(((const unsigned short*)p)[i]);
}
__device__ __forceinline__ int bad_f(float v){   // NaN or Inf
  return (v != v) || (fabsf(v) > 3.0e38f);
}

// ---------------------------------------------------------------------------
// Detect input dtype from Wq_hex (64x64, ~N(0,1)*0.125, never exactly huge).
// If buffers are bf16: every u16 is a bf16 with exponent ~[105,127].
// If buffers are f32: even-indexed u16s are low mantissa halves -> random
// exponent -> ~80% outside the sane window.  flag=1 means f32.
// ---------------------------------------------------------------------------
__global__ __launch_bounds__(64)
void detect_kernel(const unsigned short* __restrict__ wq, int* __restrict__ flag){
  if (threadIdx.x == 0 && blockIdx.x == 0){
    int insane = 0;
    for (int i = 0; i < 256; i++){
      unsigned short u = wq[2*i];
      int e = (u >> 7) & 0xFF;
      int sane = (e >= 90 && e <= 140) || ((u & 0x7FFF) == 0);
      insane += !sane;
    }
    *flag = (insane > 64) ? 1 : 0;
  }
}

// ---------------------------------------------------------------------------
// Transpose 1024x1024, any-input-dtype -> bf16 out.
// ---------------------------------------------------------------------------
__global__ __launch_bounds__(256)
void transpose_conv(const void* __restrict__ in, unsigned short* __restrict__ out,
                    const int* __restrict__ flagp){
  int f32 = *flagp;
  __shared__ unsigned short t[32][33];
  int lc = threadIdx.x & 31;
  int lr = threadIdx.x >> 5;            // 0..7
  int c0 = blockIdx.x * 32, r0 = blockIdx.y * 32;
  #pragma unroll
  for (int i = 0; i < 4; i++){
    int r = lr + i*8;
    t[r][lc] = f2b(ldf(in, (size_t)(r0 + r)*DDIM + c0 + lc, f32));
  }
  __syncthreads();
  #pragma unroll
  for (int i = 0; i < 4; i++){
    int r = lr + i*8;
    out[(size_t)(c0 + r)*DDIM + r0 + lc] = t[lc][r];
  }
}

// ---------------------------------------------------------------------------
// bc[n] = bo[n] + sum_k bv[k] * Wo[k][n]
// ---------------------------------------------------------------------------
__global__ __launch_bounds__(256)
void bc_kernel(const void* __restrict__ bv, const void* __restrict__ Wo,
               const void* __restrict__ bo, float* __restrict__ bc,
               const int* __restrict__ flagp){
  int f32 = *flagp;
  __shared__ float part[4][64];
  int tid = threadIdx.x, lane = tid & 63, w = tid >> 6;
  int n = blockIdx.x * 64 + lane;
  float acc = 0.f;
  int k0 = w * 256;
  for (int k = k0; k < k0 + 256; k++)
    acc += ldf(bv, k, f32) * ldf(Wo, (size_t)k*DDIM + n, f32);
  part[w][lane] = acc;
  __syncthreads();
  if (w == 0)
    bc[n] = part[0][lane] + part[1][lane] + part[2][lane] + part[3][lane]
          + ldf(bo, n, f32);
}

// ---------------------------------------------------------------------------
// qn = l2norm(hex_weights @ Wq_hex), f32 out. Block: 4 tokens x 64 lanes.
// ---------------------------------------------------------------------------
__global__ __launch_bounds__(256)
void normq_kernel(const void* __restrict__ hexw, const void* __restrict__ Wq,
                  float* __restrict__ qn, const int* __restrict__ flagp){
  int f32 = *flagp;
  __shared__ float Wsh[64*64];
  __shared__ float hx[4][64];
  int tid = threadIdx.x;
  #pragma unroll
  for (int i = 0; i < 16; i++){ int e = tid + i*256; Wsh[e] = ldf(Wq, e, f32); }
  int w = tid >> 6, j = tid & 63;
  int t = blockIdx.x * 4 + w;
  hx[w][j] = ldf(hexw, (size_t)t*64 + j, f32);
  __syncthreads();
  float s = 0.f;
  #pragma unroll
  for (int h = 0; h < 64; h++) s += hx[w][h] * Wsh[h*64 + j];
  float ss = s*s;
  #pragma unroll
  for (int off = 32; off >= 1; off >>= 1) ss += __shfl_xor(ss, off, 64);
  qn[(size_t)t*64 + j] = s / fmaxf(sqrtf(ss), 1e-12f);
}

// ---------------------------------------------------------------------------
// dkn = l2norm(doc_keys), f32 out. Block: 4 rows x 64 lanes.
// ---------------------------------------------------------------------------
__global__ __launch_bounds__(256)
void normk_kernel(const void* __restrict__ dkeys, float* __restrict__ dkn,
                  const int* __restrict__ flagp){
  int f32 = *flagp;
  int tid = threadIdx.x;
  int w = tid >> 6, j = tid & 63;
  int t = blockIdx.x * 4 + w;
  float v = ldf(dkeys, (size_t)t*64 + j, f32);
  float ss = v*v;
  #pragma unroll
  for (int off = 32; off >= 1; off >>= 1) ss += __shfl_xor(ss, off, 64);
  dkn[(size_t)t*64 + j] = v / fmaxf(sqrtf(ss), 1e-12f);
}

// ---------------------------------------------------------------------------
// Fused sim + top-8 + softmax (round-3 minimal-surface version, unchanged).
// NaN-safe: NaN scores never insert (comparison false), softmax of real
// scores in [-1,1] cannot produce NaN.
// ---------------------------------------------------------------------------
__global__ __launch_bounds__(512)
void topk_kernel(const float* __restrict__ qn, const float* __restrict__ dkn,
                 float* __restrict__ wout, int* __restrict__ iout){
  __shared__ float msc[8][64][8];
  __shared__ int   mix[8][64][8];
  int tid  = threadIdx.x;
  int sp   = tid >> 6;
  int lane = tid & 63;
  int token = blockIdx.x * 64 + lane;

  float q[64];
  #pragma unroll
  for (int c = 0; c < 64; c += 4){
    float4 v = *(const float4*)(qn + (size_t)token*64 + c);
    q[c] = v.x; q[c+1] = v.y; q[c+2] = v.z; q[c+3] = v.w;
  }

  float ts[8]; int ti[8];
  #pragma unroll
  for (int k = 0; k < 8; k++){ ts[k] = -1e30f; ti[k] = 0; }
  float tmin = -1e30f;

  for (int d = 0; d < 512; d++){
    int doc = sp*512 + d;
    const float4* kr = (const float4*)(dkn + (size_t)doc*64);
    float s = 0.f;
    #pragma unroll
    for (int c = 0; c < 16; c++){
      float4 kv = kr[c];
      s += q[4*c]*kv.x + q[4*c+1]*kv.y + q[4*c+2]*kv.z + q[4*c+3]*kv.w;
    }
    if (s > tmin){
      int sl = 0; float m = ts[0];
      #pragma unroll
      for (int k = 1; k < 8; k++) if (ts[k] < m){ m = ts[k]; sl = k; }
      ts[sl] = s; ti[sl] = doc;
      m = ts[0];
      #pragma unroll
      for (int k = 1; k < 8; k++) m = fminf(m, ts[k]);
      tmin = m;
    }
  }

  #pragma unroll
  for (int k = 0; k < 8; k++){ msc[sp][lane][k] = ts[k]; mix[sp][lane][k] = ti[k]; }
  __syncthreads();

  if (tid < 64){
    float sel_s[8]; int sel_i[8];
    for (int r = 0; r < 8; r++){
      float bs = -1e31f; int bi = 0x7fffffff; int bsp = 0, bk = 0;
      for (int spp = 0; spp < 8; spp++)
        #pragma unroll
        for (int k = 0; k < 8; k++){
          float s = msc[spp][tid][k]; int id = mix[spp][tid][k];
          if (s > bs || (s == bs && id < bi)){ bs = s; bi = id; bsp = spp; bk = k; }
        }
      msc[bsp][tid][bk] = -1e31f;
      sel_s[r] = bs; sel_i[r] = bi;
    }
    float mx = sel_s[0];
    float e[8], sum = 0.f;
    #pragma unroll
    for (int k = 0; k < 8; k++){ e[k] = expf(sel_s[k] - mx); sum += e[k]; }
    float inv = 1.f / sum;
    size_t t2 = (size_t)blockIdx.x * 64 + tid;
    #pragma unroll
    for (int k = 0; k < 8; k++){
      wout[t2*8 + k] = e[k] * inv;
      iout[t2*8 + k] = sel_i[k];
    }
  }
}

// ---------------------------------------------------------------------------
// C(M,N) = A(M,K) @ Bt(N,K)^T -> bf16 C.  A is raw-input (flag dtype) when
// araw=1, else bf16.  Bt always bf16.  128x128 tile, BK=32, 16x16x32 MFMA.
// ---------------------------------------------------------------------------
__global__ __launch_bounds__(256)
void gemm_bt_kernel(const void* __restrict__ A, const unsigned short* __restrict__ Bt,
                    unsigned short* __restrict__ C, int M, int N, int K,
                    const int* __restrict__ flagp, int araw){
  int f32 = araw ? *flagp : 0;
  __shared__ __align__(16) short As[128*32];
  __shared__ __align__(16) short Bs[128*32];
  int tid  = threadIdx.x;
  int lane = tid & 63;
  int wv   = tid >> 6;
  int wm = wv & 1, wn = wv >> 1;
  size_t bm = (size_t)blockIdx.x * 128, bn = (size_t)blockIdx.y * 128;

  f32x4 acc[4][4];
  #pragma unroll
  for (int i = 0; i < 4; i++)
    #pragma unroll
    for (int j = 0; j < 4; j++) acc[i][j] = (f32x4){0.f, 0.f, 0.f, 0.f};

  size_t aoff = (bm + (size_t)(tid >> 2))*K + (tid & 3)*8;
  const unsigned short* Bg = Bt + (bn + (size_t)(tid >> 2))*K + (tid & 3)*8;

  for (int k0 = 0; k0 < K; k0 += 32){
    short8 a0, a1;
    if (f32){
      const float* Af = (const float*)A;
      const float* p0 = Af + aoff + k0;
      const float* p1 = p0 + (size_t)64*K;
      float4 u0 = *(const float4*)p0, u1 = *(const float4*)(p0+4);
      float4 v0 = *(const float4*)p1, v1 = *(const float4*)(p1+4);
      a0 = (short8){(short)f2b(u0.x),(short)f2b(u0.y),(short)f2b(u0.z),(short)f2b(u0.w),
                    (short)f2b(u1.x),(short)f2b(u1.y),(short)f2b(u1.z),(short)f2b(u1.w)};
      a1 = (short8){(short)f2b(v0.x),(short)f2b(v0.y),(short)f2b(v0.z),(short)f2b(v0.w),
                    (short)f2b(v1.x),(short)f2b(v1.y),(short)f2b(v1.z),(short)f2b(v1.w)};
    } else {
      const unsigned short* Ab = (const unsigned short*)A;
      a0 = *(const short8*)(Ab + aoff + k0);
      a1 = *(const short8*)(Ab + aoff + (size_t)64*K + k0);
    }
    short8 b0 = *(const short8*)(Bg + k0);
    short8 b1 = *(const short8*)(Bg + (size_t)64*K + k0);
    __syncthreads();
    *(short8*)&As[tid*8]        = a0;
    *(short8*)&As[2048 + tid*8] = a1;
    *(short8*)&Bs[tid*8]        = b0;
    *(short8*)&Bs[2048 + tid*8] = b1;
    __syncthreads();

    short8 af[4], bf[4];
    int kb = (lane >> 4) * 8;
    int rA = wm*64 + (lane & 15);
    int rB = wn*64 + (lane & 15);
    #pragma unroll
    for (int i = 0; i < 4; i++) af[i] = *(const short8*)&As[(rA + i*16)*32 + kb];
    #pragma unroll
    for (int i = 0; i < 4; i++) bf[i] = *(const short8*)&Bs[(rB + i*16)*32 + kb];
    #pragma unroll
    for (int i = 0; i < 4; i++)
      #pragma unroll
      for (int j = 0; j < 4; j++)
        acc[i][j] = __builtin_amdgcn_mfma_f32_16x16x32_bf16(af[i], bf[j], acc[i][j], 0, 0, 0);
  }

  int ci = lane & 15, rg = lane >> 4;
  #pragma unroll
  for (int i = 0; i < 4; i++)
    #pragma unroll
    for (int j = 0; j < 4; j++)
      #pragma unroll
      for (int r = 0; r < 4; r++){
        size_t row = bm + wm*64 + i*16 + rg*4 + r;
        size_t col = bn + wn*64 + j*16 + ci;
        C[row*(size_t)N + col] = f2b(acc[i][j][r]);
      }
}

// ---------------------------------------------------------------------------
// out[t][c] = x[t][c] + g*(sum_k w[t,k]*P[idx[t,k]][c] + bc[c])
// NaN telemetry: any non-finite intermediate is replaced by 1000*mask so the
// harness absmax identifies the culprit instead of printing nan.
//   mask bits: 1=wsm  2=P-gather  4=bc  8=x  16=gate  32=final
// ---------------------------------------------------------------------------
__global__ __launch_bounds__(256)
void output_kernel(const void* __restrict__ x, const float* __restrict__ wsm,
                   const int* __restrict__ idx, const unsigned short* __restrict__ P,
                   const float* __restrict__ bc, const void* __restrict__ gate,
                   void* __restrict__ out, const int* __restrict__ flagp){
  int f32 = *flagp;
  __shared__ float ws8[8]; __shared__ int is8[8];
  int t = blockIdx.x, tid = threadIdx.x;
  if (tid < 8){
    ws8[tid] = wsm[(size_t)t*8 + tid];
    int ii = idx[(size_t)t*8 + tid];
    is8[tid] = ii < 0 ? 0 : (ii > NDOCS-1 ? NDOCS-1 : ii);
  }
  __syncthreads();
  int wbad = 0;
  #pragma unroll
  for (int k = 0; k < 8; k++) wbad |= bad_f(ws8[k]);
  float gv = ldf(gate, 0, f32);
  int gbad = bad_f(gv);
  float g = 1.f / (1.f + expf(-gv));
  int c = tid * 4;
  float a[4] = {0.f, 0.f, 0.f, 0.f};
  #pragma unroll
  for (int k = 0; k < 8; k++){
    ushort4 u = *(const ushort4*)(P + (size_t)is8[k]*DDIM + c);
    float w = ws8[k];
    a[0] += w * b2f(u.x); a[1] += w * b2f(u.y); a[2] += w * b2f(u.z); a[3] += w * b2f(u.w);
  }
  float xv[4], bcv[4];
  if (f32){
    float4 xf = *(const float4*)((const float*)x + (size_t)t*DDIM + c);
    xv[0]=xf.x; xv[1]=xf.y; xv[2]=xf.z; xv[3]=xf.w;
  } else {
    ushort4 xu = *(const ushort4*)((const unsigned short*)x + (size_t)t*DDIM + c);
    xv[0]=b2f(xu.x); xv[1]=b2f(xu.y); xv[2]=b2f(xu.z); xv[3]=b2f(xu.w);
  }
  #pragma unroll
  for (int j = 0; j < 4; j++) bcv[j] = bc[c+j];

  float res[4];
  #pragma unroll
  for (int j = 0; j < 4; j++){
    int mask = 0;
    if (wbad)          mask |= 1;
    if (bad_f(a[j]))   mask |= 2;
    if (bad_f(bcv[j])) mask |= 4;
    if (bad_f(xv[j]))  mask |= 8;
    if (gbad)          mask |= 16;
    float v = xv[j] + g * (a[j] + bcv[j]);
    if (bad_f(v))      mask |= 32;
    res[j] = mask ? 1000.0f * (float)mask : v;
  }
  if (f32){
    float4 o; o.x=res[0]; o.y=res[1]; o.z=res[2]; o.w=res[3];
    *(float4*)((float*)out + (size_t)t*DDIM + c) = o;
  } else {
    ushort4 o; o.x=f2b(res[0]); o.y=f2b(res[1]); o.z=f2b(res[2]); o.w=f2b(res[3]);
    *(ushort4*)((unsigned short*)out + (size_t)t*DDIM + c) = o;
  }
}

// Fallback: "ws too small" signature (absmax == ref max, no fault)
__global__ __launch_bounds__(256)
void zero_out_kernel(unsigned short* __restrict__ out){
  size_t i = ((size_t)blockIdx.x * 256 + threadIdx.x) * 4;
  *(ushort4*)(out + i) = (ushort4){0,0,0,0};
}

// ---------------------------------------------------------------------------
extern "C" void kernel_launch(void* const* d_in, const int* in_sizes, int n_in,
                              void* d_out, int out_size, void* d_ws, size_t ws_size,
                              hipStream_t stream){
  (void)in_sizes; (void)n_in; (void)out_size;
  const void* x     = d_in[0];
  const void* hexw  = d_in[1];
  const void* dkeys = d_in[2];
  const void* dvals = d_in[3];
  const void* Wqh   = d_in[4];
  // d_in[5]=Wq, d_in[6]=Wk, d_in[8]=bq, d_in[9]=bk: dead (degenerate attention)
  const void* Wv    = d_in[7];
  const void* bv    = d_in[10];
  const void* Wo    = d_in[11];
  const void* bo    = d_in[12];
  const void* Wdoc  = d_in[13];
  const void* gate  = d_in[14];

  const size_t NEED = ((size_t)22 << 20) + 8192;
  if (ws_size < NEED){
    zero_out_kernel<<<NTOK*DDIM/1024, 256, 0, stream>>>((unsigned short*)d_out);
    return;
  }

  // Workspace layout (lifetime-overlapped), 22 MB + 8 KB:
  // Phase 1: T0 [0,2) T1 [2,4) T2 [4,6) Pa [6,14) Pb [14,22) MB, bc [22M,+4K),
  //          flag at 22M+4K.
  // Phase 2 (T0..T2 dead): qn [0,4) dkn [4,5) wsm [5,5.5) idx [5.5,6) MB.
  char* ws = (char*)d_ws;
  unsigned short* T0 = (unsigned short*)(ws);
  unsigned short* T1 = (unsigned short*)(ws + ((size_t)2  << 20));
  unsigned short* T2 = (unsigned short*)(ws + ((size_t)4  << 20));
  unsigned short* Pa = (unsigned short*)(ws + ((size_t)6  << 20));
  unsigned short* Pb = (unsigned short*)(ws + ((size_t)14 << 20));
  float* qn          = (float*)(ws);
  float* dkn         = (float*)(ws + ((size_t)4 << 20));
  float* wsm         = (float*)(ws + ((size_t)5 << 20));
  int*   idx         = (int*)  (ws + ((size_t)5 << 20) + (512 << 10));
  float* bc          = (float*)(ws + ((size_t)22 << 20));
  int*   flag        = (int*)  (ws + ((size_t)22 << 20) + 4096);

  detect_kernel<<<1, 64, 0, stream>>>((const unsigned short*)Wqh, flag);

  // Phase 1: Pb(final) = dvals @ W_doc @ Wv @ Wo (bf16 GEMMs); bc = bv@Wo+bo.
  transpose_conv<<<dim3(32,32), 256, 0, stream>>>(Wdoc, T0, flag);
  transpose_conv<<<dim3(32,32), 256, 0, stream>>>(Wv,   T1, flag);
  transpose_conv<<<dim3(32,32), 256, 0, stream>>>(Wo,   T2, flag);
  bc_kernel<<<16, 256, 0, stream>>>(bv, Wo, bo, bc, flag);
  gemm_bt_kernel<<<dim3(NDOCS/128, DDIM/128), 256, 0, stream>>>(dvals, T0, Pb, NDOCS, DDIM, DDIM, flag, 1);
  gemm_bt_kernel<<<dim3(NDOCS/128, DDIM/128), 256, 0, stream>>>(Pb,    T1, Pa, NDOCS, DDIM, DDIM, flag, 0);
  gemm_bt_kernel<<<dim3(NDOCS/128, DDIM/128), 256, 0, stream>>>(Pa,    T2, Pb, NDOCS, DDIM, DDIM, flag, 0);

  // Phase 2: retrieval
  normq_kernel<<<NTOK/4, 256, 0, stream>>>(hexw, Wqh, qn, flag);
  normk_kernel<<<NDOCS/4, 256, 0, stream>>>(dkeys, dkn, flag);
  topk_kernel<<<NTOK/64, 512, 0, stream>>>(qn, dkn, wsm, idx);

  // out = x + sigmoid(gate) * (gather-combine(Pb) + bc)
  output_kernel<<<NTOK, 256, 0, stream>>>(x, wsm, idx, Pb, bc, gate, d_out, flag);
}

// Round 5
// 907.515 us; speedup vs baseline: 1.1282x; 1.1282x over previous
//
#include <hip/hip_runtime.h>
#include <math.h>

// Problem constants (inputs/outputs are f32; verified round 4)
#define NTOK  16384   // B*T
#define DDIM  1024
#define NDOCS 4096
#define NSLICE 8      // doc slices for topk_part

typedef __attribute__((ext_vector_type(8))) short short8;
typedef __attribute__((ext_vector_type(4))) float f32x4;

__device__ __forceinline__ float b2f(unsigned short u){
  union { unsigned int i; float f; } v; v.i = ((unsigned int)u) << 16; return v.f;
}
__device__ __forceinline__ unsigned short f2b(float f){
  union { float f; unsigned int i; } v; v.f = f;
  unsigned int r = v.i + 0x7fffu + ((v.i >> 16) & 1u);   // RNE
  return (unsigned short)(r >> 16);
}

// ---------------------------------------------------------------------------
// Transpose 1024x1024, f32 in -> bf16 out.
// ---------------------------------------------------------------------------
__global__ __launch_bounds__(256)
void transpose_f32_bf16(const float* __restrict__ in, unsigned short* __restrict__ out){
  __shared__ unsigned short t[32][33];
  int lc = threadIdx.x & 31;
  int lr = threadIdx.x >> 5;            // 0..7
  int c0 = blockIdx.x * 32, r0 = blockIdx.y * 32;
  #pragma unroll
  for (int i = 0; i < 4; i++){
    int r = lr + i*8;
    t[r][lc] = f2b(in[(size_t)(r0 + r)*DDIM + c0 + lc]);
  }
  __syncthreads();
  #pragma unroll
  for (int i = 0; i < 4; i++){
    int r = lr + i*8;
    out[(size_t)(c0 + r)*DDIM + r0 + lc] = t[lc][r];
  }
}

// ---------------------------------------------------------------------------
// bc[n] = bo[n] + sum_k bv[k] * Wo[k][n]   (all f32)
// ---------------------------------------------------------------------------
__global__ __launch_bounds__(256)
void bc_kernel(const float* __restrict__ bv, const float* __restrict__ Wo,
               const float* __restrict__ bo, float* __restrict__ bc){
  __shared__ float part[4][64];
  int tid = threadIdx.x, lane = tid & 63, w = tid >> 6;
  int n = blockIdx.x * 64 + lane;
  float acc = 0.f;
  int k0 = w * 256;
  for (int k = k0; k < k0 + 256; k++)
    acc += bv[k] * Wo[(size_t)k*DDIM + n];
  part[w][lane] = acc;
  __syncthreads();
  if (w == 0)
    bc[n] = part[0][lane] + part[1][lane] + part[2][lane] + part[3][lane] + bo[n];
}

// ---------------------------------------------------------------------------
// qn = l2norm(hex_weights @ Wq_hex), f32 out. Block: 4 tokens x 64 lanes.
// ---------------------------------------------------------------------------
__global__ __launch_bounds__(256)
void normq_kernel(const float* __restrict__ hexw, const float* __restrict__ Wq,
                  float* __restrict__ qn){
  __shared__ float Wsh[64*64];
  __shared__ float hx[4][64];
  int tid = threadIdx.x;
  #pragma unroll
  for (int i = 0; i < 16; i++){ int e = tid + i*256; Wsh[e] = Wq[e]; }
  int w = tid >> 6, j = tid & 63;
  int t = blockIdx.x * 4 + w;
  hx[w][j] = hexw[(size_t)t*64 + j];
  __syncthreads();
  float s = 0.f;
  #pragma unroll
  for (int h = 0; h < 64; h++) s += hx[w][h] * Wsh[h*64 + j];
  float ss = s*s;
  #pragma unroll
  for (int off = 32; off >= 1; off >>= 1) ss += __shfl_xor(ss, off, 64);
  qn[(size_t)t*64 + j] = s / fmaxf(sqrtf(ss), 1e-12f);
}

// ---------------------------------------------------------------------------
// dkn = l2norm(doc_keys), f32 out. Block: 4 rows x 64 lanes.
// ---------------------------------------------------------------------------
__global__ __launch_bounds__(256)
void normk_kernel(const float* __restrict__ dkeys, float* __restrict__ dkn){
  int tid = threadIdx.x;
  int w = tid >> 6, j = tid & 63;
  int t = blockIdx.x * 4 + w;
  float v = dkeys[(size_t)t*64 + j];
  float ss = v*v;
  #pragma unroll
  for (int off = 32; off >= 1; off >>= 1) ss += __shfl_xor(ss, off, 64);
  dkn[(size_t)t*64 + j] = v / fmaxf(sqrtf(ss), 1e-12f);
}

// ---------------------------------------------------------------------------
// topk_part: per (64-token block, doc slice) partial top-8.
// Grid (NTOK/64, NSLICE). Block 256 = 4 waves; wave w scans 128 docs of the
// slice. Lane l owns token blockIdx.x*64+l (k-row loads broadcast across the
// wave). q stays in registers (launch_bounds(256,2) -> up to 256 VGPRs).
// ---------------------------------------------------------------------------
__global__ __launch_bounds__(256, 2)
void topk_part(const float* __restrict__ qn, const float* __restrict__ dkn,
               float* __restrict__ cs, int* __restrict__ ci){
  __shared__ float msc[4][64][9];   // pad stride 9: no 8-way bank conflicts
  __shared__ int   mix[4][64][9];
  int tid  = threadIdx.x;
  int wv   = tid >> 6;
  int lane = tid & 63;
  int token = blockIdx.x * 64 + lane;

  float4 qv[16];
  const float4* qp = (const float4*)(qn + (size_t)token*64);
  #pragma unroll
  for (int c = 0; c < 16; c++) qv[c] = qp[c];

  float ts[8]; int ti[8];
  #pragma unroll
  for (int k = 0; k < 8; k++){ ts[k] = -1e30f; ti[k] = 0; }
  float tmin = -1e30f;

  int dbase = blockIdx.y * (NDOCS/NSLICE) + wv * 128;
  for (int d = 0; d < 128; d++){
    const float4* kr = (const float4*)(dkn + (size_t)(dbase + d)*64);
    float s0 = 0.f, s1 = 0.f, s2 = 0.f, s3 = 0.f;
    #pragma unroll
    for (int c = 0; c < 16; c += 4){
      float4 k0 = kr[c], k1 = kr[c+1], k2 = kr[c+2], k3 = kr[c+3];
      s0 += qv[c  ].x*k0.x + qv[c  ].y*k0.y + qv[c  ].z*k0.z + qv[c  ].w*k0.w;
      s1 += qv[c+1].x*k1.x + qv[c+1].y*k1.y + qv[c+1].z*k1.z + qv[c+1].w*k1.w;
      s2 += qv[c+2].x*k2.x + qv[c+2].y*k2.y + qv[c+2].z*k2.z + qv[c+2].w*k2.w;
      s3 += qv[c+3].x*k3.x + qv[c+3].y*k3.y + qv[c+3].z*k3.z + qv[c+3].w*k3.w;
    }
    float s = (s0 + s1) + (s2 + s3);
    if (s > tmin){
      int sl = 0; float m = ts[0];
      #pragma unroll
      for (int k = 1; k < 8; k++) if (ts[k] < m){ m = ts[k]; sl = k; }
      ts[sl] = s; ti[sl] = dbase + d;
      m = ts[0];
      #pragma unroll
      for (int k = 1; k < 8; k++) m = fminf(m, ts[k]);
      tmin = m;
    }
  }

  #pragma unroll
  for (int k = 0; k < 8; k++){ msc[wv][lane][k] = ts[k]; mix[wv][lane][k] = ti[k]; }
  __syncthreads();

  if (tid < 64){
    // merge 4 waves x 8 -> slice top-8 (descending, ties -> lower id)
    float sel_s[8]; int sel_i[8];
    for (int r = 0; r < 8; r++){
      float bs = -1e31f; int bi = 0x7fffffff; int bw = 0, bk = 0;
      for (int w = 0; w < 4; w++)
        #pragma unroll
        for (int k = 0; k < 8; k++){
          float s = msc[w][tid][k]; int id = mix[w][tid][k];
          if (s > bs || (s == bs && id < bi)){ bs = s; bi = id; bw = w; bk = k; }
        }
      msc[bw][tid][bk] = -1e31f;
      sel_s[r] = bs; sel_i[r] = bi;
    }
    size_t base = ((size_t)(blockIdx.x*64 + tid) * NSLICE + blockIdx.y) * 8;
    #pragma unroll
    for (int k = 0; k < 8; k++){ cs[base + k] = sel_s[k]; ci[base + k] = sel_i[k]; }
  }
}

// ---------------------------------------------------------------------------
// topk_merge: per token merge NSLICE x 8 candidates -> global top-8 + softmax.
// One thread per token.
// ---------------------------------------------------------------------------
__global__ __launch_bounds__(256)
void topk_merge(const float* __restrict__ cs, const int* __restrict__ ci,
                float* __restrict__ wout, int* __restrict__ iout){
  int t = blockIdx.x * 256 + threadIdx.x;
  float s[64]; int id[64];
  const float4* sp = (const float4*)(cs + (size_t)t*64);
  const int4*   ip = (const int4*)  (ci + (size_t)t*64);
  #pragma unroll
  for (int i = 0; i < 16; i++){
    float4 v = sp[i]; int4 w = ip[i];
    s[4*i]=v.x; s[4*i+1]=v.y; s[4*i+2]=v.z; s[4*i+3]=v.w;
    id[4*i]=w.x; id[4*i+1]=w.y; id[4*i+2]=w.z; id[4*i+3]=w.w;
  }
  float sel_s[8]; int sel_i[8];
  for (int r = 0; r < 8; r++){
    float bs = -1e31f; int bi = 0x7fffffff; int bj = 0;
    for (int j = 0; j < 64; j++){
      if (s[j] > bs || (s[j] == bs && id[j] < bi)){ bs = s[j]; bi = id[j]; bj = j; }
    }
    s[bj] = -1e31f;
    sel_s[r] = bs; sel_i[r] = bi;
  }
  float mx = sel_s[0];
  float e[8], sum = 0.f;
  #pragma unroll
  for (int k = 0; k < 8; k++){ e[k] = expf(sel_s[k] - mx); sum += e[k]; }
  float inv = 1.f / sum;
  #pragma unroll
  for (int k = 0; k < 8; k++){
    wout[(size_t)t*8 + k] = e[k] * inv;
    iout[(size_t)t*8 + k] = sel_i[k];
  }
}

// ---------------------------------------------------------------------------
// C(M,N) = A(M,K) @ Bt(N,K)^T -> bf16 C.  AF32: A is f32 (convert in staging).
// TSTORE: store C transposed (C[col*M+row]).  128x128 tile, BK=32, 4 waves,
// 16x16x32 MFMA.
// ---------------------------------------------------------------------------
template<int AF32, int TSTORE>
__global__ __launch_bounds__(256)
void gemm_bt_kernel(const void* __restrict__ A, const unsigned short* __restrict__ Bt,
                    unsigned short* __restrict__ C, int M, int N, int K){
  __shared__ __align__(16) short As[128*32];
  __shared__ __align__(16) short Bs[128*32];
  int tid  = threadIdx.x;
  int lane = tid & 63;
  int wv   = tid >> 6;
  int wm = wv & 1, wn = wv >> 1;
  size_t bm = (size_t)blockIdx.x * 128, bn = (size_t)blockIdx.y * 128;

  f32x4 acc[4][4];
  #pragma unroll
  for (int i = 0; i < 4; i++)
    #pragma unroll
    for (int j = 0; j < 4; j++) acc[i][j] = (f32x4){0.f, 0.f, 0.f, 0.f};

  size_t aoff = (bm + (size_t)(tid >> 2))*K + (tid & 3)*8;
  const unsigned short* Bg = Bt + (bn + (size_t)(tid >> 2))*K + (tid & 3)*8;

  for (int k0 = 0; k0 < K; k0 += 32){
    short8 a0, a1;
    if (AF32){
      const float* Af = (const float*)A;
      const float* p0 = Af + aoff + k0;
      const float* p1 = p0 + (size_t)64*K;
      float4 u0 = *(const float4*)p0, u1 = *(const float4*)(p0+4);
      float4 v0 = *(const float4*)p1, v1 = *(const float4*)(p1+4);
      a0 = (short8){(short)f2b(u0.x),(short)f2b(u0.y),(short)f2b(u0.z),(short)f2b(u0.w),
                    (short)f2b(u1.x),(short)f2b(u1.y),(short)f2b(u1.z),(short)f2b(u1.w)};
      a1 = (short8){(short)f2b(v0.x),(short)f2b(v0.y),(short)f2b(v0.z),(short)f2b(v0.w),
                    (short)f2b(v1.x),(short)f2b(v1.y),(short)f2b(v1.z),(short)f2b(v1.w)};
    } else {
      const unsigned short* Ab = (const unsigned short*)A;
      a0 = *(const short8*)(Ab + aoff + k0);
      a1 = *(const short8*)(Ab + aoff + (size_t)64*K + k0);
    }
    short8 b0 = *(const short8*)(Bg + k0);
    short8 b1 = *(const short8*)(Bg + (size_t)64*K + k0);
    __syncthreads();
    *(short8*)&As[tid*8]        = a0;
    *(short8*)&As[2048 + tid*8] = a1;
    *(short8*)&Bs[tid*8]        = b0;
    *(short8*)&Bs[2048 + tid*8] = b1;
    __syncthreads();

    short8 af[4], bf[4];
    int kb = (lane >> 4) * 8;
    int rA = wm*64 + (lane & 15);
    int rB = wn*64 + (lane & 15);
    #pragma unroll
    for (int i = 0; i < 4; i++) af[i] = *(const short8*)&As[(rA + i*16)*32 + kb];
    #pragma unroll
    for (int i = 0; i < 4; i++) bf[i] = *(const short8*)&Bs[(rB + i*16)*32 + kb];
    #pragma unroll
    for (int i = 0; i < 4; i++)
      #pragma unroll
      for (int j = 0; j < 4; j++)
        acc[i][j] = __builtin_amdgcn_mfma_f32_16x16x32_bf16(af[i], bf[j], acc[i][j], 0, 0, 0);
  }

  int ci = lane & 15, rg = lane >> 4;
  #pragma unroll
  for (int i = 0; i < 4; i++)
    #pragma unroll
    for (int j = 0; j < 4; j++)
      #pragma unroll
      for (int r = 0; r < 4; r++){
        size_t row = bm + wm*64 + i*16 + rg*4 + r;
        size_t col = bn + wn*64 + j*16 + ci;
        if (TSTORE) C[col*(size_t)M + row] = f2b(acc[i][j][r]);
        else        C[row*(size_t)N + col] = f2b(acc[i][j][r]);
      }
}

// ---------------------------------------------------------------------------
// out[t][c] = x[t][c] + g*(sum_k w[t,k]*P[idx[t,k]][c] + bc[c])   (f32 I/O)
// ---------------------------------------------------------------------------
__global__ __launch_bounds__(256)
void output_kernel(const float* __restrict__ x, const float* __restrict__ wsm,
                   const int* __restrict__ idx, const unsigned short* __restrict__ P,
                   const float* __restrict__ bc, const float* __restrict__ gate,
                   float* __restrict__ out){
  __shared__ float ws8[8]; __shared__ int is8[8];
  int t = blockIdx.x, tid = threadIdx.x;
  if (tid < 8){
    ws8[tid] = wsm[(size_t)t*8 + tid];
    int ii = idx[(size_t)t*8 + tid];
    is8[tid] = ii < 0 ? 0 : (ii > NDOCS-1 ? NDOCS-1 : ii);
  }
  __syncthreads();
  float g = 1.f / (1.f + expf(-gate[0]));
  int c = tid * 4;
  float a0 = 0.f, a1 = 0.f, a2 = 0.f, a3 = 0.f;
  #pragma unroll
  for (int k = 0; k < 8; k++){
    ushort4 u = *(const ushort4*)(P + (size_t)is8[k]*DDIM + c);
    float w = ws8[k];
    a0 += w * b2f(u.x); a1 += w * b2f(u.y); a2 += w * b2f(u.z); a3 += w * b2f(u.w);
  }
  float4 xf = *(const float4*)(x + (size_t)t*DDIM + c);
  float4 o;
  o.x = xf.x + g * (a0 + bc[c]);
  o.y = xf.y + g * (a1 + bc[c+1]);
  o.z = xf.z + g * (a2 + bc[c+2]);
  o.w = xf.w + g * (a3 + bc[c+3]);
  *(float4*)(out + (size_t)t*DDIM + c) = o;
}

// Fallback: "ws too small" signature (absmax == ref max, no fault)
__global__ __launch_bounds__(256)
void zero_out_kernel(float* __restrict__ out){
  size_t i = ((size_t)blockIdx.x * 256 + threadIdx.x) * 4;
  *(float4*)(out + i) = (float4){0.f,0.f,0.f,0.f};
}

// ---------------------------------------------------------------------------
extern "C" void kernel_launch(void* const* d_in, const int* in_sizes, int n_in,
                              void* d_out, int out_size, void* d_ws, size_t ws_size,
                              hipStream_t stream){
  (void)in_sizes; (void)n_in; (void)out_size;
  const float* x     = (const float*)d_in[0];
  const float* hexw  = (const float*)d_in[1];
  const float* dkeys = (const float*)d_in[2];
  const float* dvals = (const float*)d_in[3];
  const float* Wqh   = (const float*)d_in[4];
  // d_in[5]=Wq, d_in[6]=Wk, d_in[8]=bq, d_in[9]=bk: dead (degenerate attention)
  const float* Wv    = (const float*)d_in[7];
  const float* bv    = (const float*)d_in[10];
  const float* Wo    = (const float*)d_in[11];
  const float* bo    = (const float*)d_in[12];
  const float* Wdoc  = (const float*)d_in[13];
  const float* gate  = (const float*)d_in[14];
  float* out = (float*)d_out;

  const size_t NEED = ((size_t)22 << 20) + 4096;
  if (ws_size < NEED){
    zero_out_kernel<<<NTOK*DDIM/1024, 256, 0, stream>>>(out);
    return;
  }

  // Workspace layout (lifetime-overlapped), 22 MB + 4 KB:
  //  [0,4)    qn (f32)
  //  [4,5)    dkn (f32)
  //  [5,5.5)  wsm   [5.5,6) idx
  //  [6,8)    T1 (Wv^T bf16)   -> dead after G1; cand scores [6,10) after G3
  //  [8,10)   T2 (Wo^T bf16)   -> dead after G2
  //  [10,12)  tmp (Wdoc@Wv bf16) -> dead after G2; cand ids [10,14) after G3
  //  [12,14)  WcT (Wc^T bf16)  -> dead after G3
  //  [14,22)  P = dvals @ Wc (bf16, live to end)
  //  [22M,+4K) bc (f32)
  char* ws = (char*)d_ws;
  float* qn          = (float*)(ws);
  float* dkn         = (float*)(ws + ((size_t)4 << 20));
  float* wsm         = (float*)(ws + ((size_t)5 << 20));
  int*   idx         = (int*)  (ws + ((size_t)5 << 20) + (512 << 10));
  unsigned short* T1  = (unsigned short*)(ws + ((size_t)6  << 20));
  unsigned short* T2  = (unsigned short*)(ws + ((size_t)8  << 20));
  unsigned short* tmp = (unsigned short*)(ws + ((size_t)10 << 20));
  unsigned short* WcT = (unsigned short*)(ws + ((size_t)12 << 20));
  unsigned short* P   = (unsigned short*)(ws + ((size_t)14 << 20));
  float* cs          = (float*)(ws + ((size_t)6  << 20));   // after GEMMs
  int*   ci          = (int*)  (ws + ((size_t)10 << 20));   // after GEMMs
  float* bc          = (float*)(ws + ((size_t)22 << 20));

  // Phase 1: P = dvals @ (W_doc@Wv@Wo); bc = bv@Wo + bo.
  // (degenerate attention + linear combine fold the whole tail into one
  //  gather over P; Wc built with two 1024^3 GEMMs, not three 4096-row ones)
  transpose_f32_bf16<<<dim3(32,32), 256, 0, stream>>>(Wv, T1);
  transpose_f32_bf16<<<dim3(32,32), 256, 0, stream>>>(Wo, T2);
  bc_kernel<<<16, 256, 0, stream>>>(bv, Wo, bo, bc);
  gemm_bt_kernel<1,0><<<dim3(8,8),   256, 0, stream>>>(Wdoc, T1, tmp, DDIM, DDIM, DDIM);
  gemm_bt_kernel<0,1><<<dim3(8,8),   256, 0, stream>>>(tmp,  T2, WcT, DDIM, DDIM, DDIM);
  gemm_bt_kernel<1,0><<<dim3(32,8),  256, 0, stream>>>(dvals, WcT, P, NDOCS, DDIM, DDIM);

  // Phase 2: retrieval
  normq_kernel<<<NTOK/4, 256, 0, stream>>>(hexw, Wqh, qn);
  normk_kernel<<<NDOCS/4, 256, 0, stream>>>(dkeys, dkn);
  topk_part<<<dim3(NTOK/64, NSLICE), 256, 0, stream>>>(qn, dkn, cs, ci);
  topk_merge<<<NTOK/256, 256, 0, stream>>>(cs, ci, wsm, idx);

  // out = x + sigmoid(gate) * (gather-combine(P) + bc)
  output_kernel<<<NTOK, 256, 0, stream>>>(x, wsm, idx, P, bc, gate, out);
}